// Round 1
// baseline (1029.696 us; speedup 1.0000x reference)
//
#include <hip/hip_runtime.h>
#include <float.h>

#define B 8
#define C 64
#define N 4096
#define O 64
#define KMAX 32

// ---------------- xx[b,n] = sum_c x[b,c,n]^2 ----------------
__global__ __launch_bounds__(256) void ec_xx(const float* __restrict__ x,
                                             float* __restrict__ xx) {
    int i = blockIdx.x * 256 + threadIdx.x;   // b*N + n
    int b = i >> 12;
    int n = i & (N - 1);
    const float* xb = x + (size_t)b * C * N + n;
    float acc = 0.f;
#pragma unroll
    for (int c = 0; c < C; ++c) {
        float t = xb[(size_t)c * N];
        acc += t * t;
    }
    xx[i] = acc;
}

// ---------------- d[n,m] = 2*dot(x_n,x_m) - xx[m]  (one batch) ----------------
__global__ __launch_bounds__(256) void ec_gemm(const float* __restrict__ x,
                                               const float* __restrict__ xx,
                                               float* __restrict__ d, int b) {
    __shared__ float As[C][128];
    __shared__ float Bs[C][128];
    const int m0 = blockIdx.x * 128;
    const int n0 = blockIdx.y * 128;
    const float* xb = x + (size_t)b * C * N;
    const int t = threadIdx.x;

    // stage both 64x128 tiles (float4, coalesced)
    const float4* xa = (const float4*)xb;
#pragma unroll
    for (int p = 0; p < 8; ++p) {
        int q = t + 256 * p;          // 0..2047
        int c = q >> 5;               // 64 rows
        int j4 = q & 31;              // 32 float4 per row
        float4 va = xa[(size_t)c * (N / 4) + (n0 >> 2) + j4];
        *((float4*)&As[c][j4 * 4]) = va;
        float4 vb = xa[(size_t)c * (N / 4) + (m0 >> 2) + j4];
        *((float4*)&Bs[c][j4 * 4]) = vb;
    }
    __syncthreads();

    const int tx = t & 15;            // m micro
    const int ty = t >> 4;            // n micro
    float acc[8][8] = {};
#pragma unroll 4
    for (int k = 0; k < C; ++k) {
        float a[8], bb[8];
        *(float4*)&a[0]  = *(float4*)&As[k][ty * 8];
        *(float4*)&a[4]  = *(float4*)&As[k][ty * 8 + 4];
        *(float4*)&bb[0] = *(float4*)&Bs[k][tx * 8];
        *(float4*)&bb[4] = *(float4*)&Bs[k][tx * 8 + 4];
#pragma unroll
        for (int i = 0; i < 8; ++i)
#pragma unroll
            for (int j = 0; j < 8; ++j)
                acc[i][j] += a[i] * bb[j];
    }

    float xm[8];
    *(float4*)&xm[0] = *(const float4*)&xx[(size_t)b * N + m0 + tx * 8];
    *(float4*)&xm[4] = *(const float4*)&xx[(size_t)b * N + m0 + tx * 8 + 4];
#pragma unroll
    for (int i = 0; i < 8; ++i) {
        int n = n0 + ty * 8 + i;
        float4 o0, o1;
        o0.x = 2.f * acc[i][0] - xm[0];
        o0.y = 2.f * acc[i][1] - xm[1];
        o0.z = 2.f * acc[i][2] - xm[2];
        o0.w = 2.f * acc[i][3] - xm[3];
        o1.x = 2.f * acc[i][4] - xm[4];
        o1.y = 2.f * acc[i][5] - xm[5];
        o1.z = 2.f * acc[i][6] - xm[6];
        o1.w = 2.f * acc[i][7] - xm[7];
        *(float4*)&d[(size_t)n * N + m0 + tx * 8]     = o0;
        *(float4*)&d[(size_t)n * N + m0 + tx * 8 + 4] = o1;
    }
}

// ---------------- top-k per row; 1 wave per row, 4 rows/block ----------------
__global__ __launch_bounds__(256) void ec_topk(const float* __restrict__ d,
                                               const int* __restrict__ kptr,
                                               int* __restrict__ idx, int b) {
    __shared__ float sd[4 * N];       // 64 KB
    const int n0 = blockIdx.x * 4;
    const int t = threadIdx.x;

    const float4* src = (const float4*)(d + (size_t)n0 * N);
    float4* dst = (float4*)sd;
#pragma unroll
    for (int p = 0; p < 16; ++p) dst[t + 256 * p] = src[t + 256 * p];
    __syncthreads();

    const int w = t >> 6;
    const int lane = t & 63;
    const int k = *kptr;
    float* row = sd + (size_t)w * N;
    const int n = n0 + w;
    int* out = idx + ((size_t)b * N + n) * KMAX;

    for (int r = 0; r < k; ++r) {
        float v = -FLT_MAX;
        int mi = 0;
        // lane owns m = lane + 64*tt -> conflict-free, lowest-index tie-keep
        for (int tt = 0; tt < 64; ++tt) {
            int m = lane + (tt << 6);
            float cv = row[m];
            if (cv > v) { v = cv; mi = m; }
        }
        // 64-lane argmax, tie -> lowest index (matches lax.top_k)
#pragma unroll
        for (int off = 1; off < 64; off <<= 1) {
            float ov = __shfl_xor(v, off);
            int oi = __shfl_xor(mi, off);
            if (ov > v || (ov == v && oi < mi)) { v = ov; mi = oi; }
        }
        if (lane == 0) out[r] = mi;
        if ((mi & 63) == lane) row[mi] = -FLT_MAX;
    }
}

// ---------------- u[b,m,o], v[b,n,o] ----------------
__global__ __launch_bounds__(256) void ec_uv(const float* __restrict__ x,
                                             const float* __restrict__ W,
                                             float* __restrict__ u,
                                             float* __restrict__ v) {
    __shared__ float xs[C][64];
    __shared__ float W1[C][64];
    __shared__ float Wd[C][64];
    const int blk = blockIdx.x;        // B * N/64
    const int b = blk >> 6;
    const int m0 = (blk & 63) << 6;
    const int t = threadIdx.x;

#pragma unroll
    for (int p = 0; p < 16; ++p) {
        int q = t + 256 * p;           // 4096
        int c = q >> 6, j = q & 63;
        xs[c][j] = x[(size_t)b * C * N + (size_t)c * N + m0 + j];
    }
#pragma unroll
    for (int p = 0; p < 16; ++p) {
        int q = t + 256 * p;           // (c,o) pairs, 4096
        int c = q >> 6, o = q & 63;
        float w1 = W[o * 128 + c];
        float w2 = W[o * 128 + 64 + c];
        W1[c][o] = w1;
        Wd[c][o] = w2 - w1;
    }
    __syncthreads();

    const int o = t & 63, ji = t >> 6;
#pragma unroll 1
    for (int p = 0; p < 16; ++p) {
        int j = ji + 4 * p;
        float su = 0.f, sv = 0.f;
#pragma unroll
        for (int c = 0; c < C; ++c) {
            float xv = xs[c][j];
            su += xv * W1[c][o];
            sv += xv * Wd[c][o];
        }
        size_t base = ((size_t)b * N + m0 + j) * O + o;
        u[base] = su;
        v[base] = sv;
    }
}

// ---------------- BN stats + per-(b,n,o) gather max/min ----------------
__global__ __launch_bounds__(256) void ec_stats(const float* __restrict__ u,
                                                const float* __restrict__ v,
                                                const int* __restrict__ idx,
                                                const int* __restrict__ kptr,
                                                float* __restrict__ ymax,
                                                float* __restrict__ ymin,
                                                float* __restrict__ stats) {
    const int blk = blockIdx.x;        // B * N/64
    const int b = blk >> 6;
    const int n0 = (blk & 63) << 6;
    const int t = threadIdx.x;
    const int o = t & 63, ni = t >> 6;
    const int k = *kptr;
    const float* ub = u + (size_t)b * N * O;
    float s = 0.f, s2 = 0.f;

    for (int p = 0; p < 16; ++p) {
        int n = n0 + ni * 16 + p;
        const int* ip = idx + ((size_t)b * N + n) * KMAX;
        float vv = v[((size_t)b * N + n) * O + o];
        float gmax = -FLT_MAX, gmin = FLT_MAX;
        for (int kk = 0; kk < k; ++kk) {
            int m = ip[kk];
            float g = ub[(size_t)m * O + o];
            float y = g + vv;
            s += y;
            s2 += y * y;
            gmax = fmaxf(gmax, g);
            gmin = fminf(gmin, g);
        }
        ymax[((size_t)b * N + n) * O + o] = gmax + vv;
        ymin[((size_t)b * N + n) * O + o] = gmin + vv;
    }

    __shared__ float rs[256], rs2[256];
    rs[t] = s;
    rs2[t] = s2;
    __syncthreads();
    if (t < 64) {
        float a  = rs[t] + rs[t + 64] + rs[t + 128] + rs[t + 192];
        float a2 = rs2[t] + rs2[t + 64] + rs2[t + 128] + rs2[t + 192];
        atomicAdd(&stats[t], a);
        atomicAdd(&stats[64 + t], a2);
    }
}

// ---------------- finalize BN affine ----------------
__global__ void ec_final(const float* __restrict__ stats,
                         const float* __restrict__ gamma,
                         const float* __restrict__ beta,
                         const int* __restrict__ kptr,
                         float* __restrict__ scsh) {
    int o = threadIdx.x;               // 64
    int k = *kptr;
    float M = (float)B * (float)N * (float)k;
    float mean = stats[o] / M;
    float var = stats[64 + o] / M - mean * mean;
    var = fmaxf(var, 0.f);
    float sc = gamma[o] * rsqrtf(var + 1e-5f);
    float sh = beta[o] - mean * sc;
    scsh[o] = sc;
    scsh[64 + o] = sh;
}

// ---------------- output: BN + leaky + transpose to (B,O,N) ----------------
__global__ __launch_bounds__(256) void ec_out(const float* __restrict__ ymax,
                                              const float* __restrict__ ymin,
                                              const float* __restrict__ scsh,
                                              float* __restrict__ out) {
    __shared__ float res[64][65];
    const int blk = blockIdx.x;        // B * N/64
    const int b = blk >> 6;
    const int n0 = (blk & 63) << 6;
    const int t = threadIdx.x;
    {
        const int o = t & 63, ni = t >> 6;
        float sc = scsh[o], sh = scsh[64 + o];
#pragma unroll 1
        for (int p = 0; p < 16; ++p) {
            int nl = ni * 16 + p;
            size_t a = ((size_t)b * N + n0 + nl) * O + o;
            float y = (sc >= 0.f) ? ymax[a] : ymin[a];
            float z = sc * y + sh;
            res[nl][o] = (z >= 0.f) ? z : 0.2f * z;
        }
    }
    __syncthreads();
    {
        const int j = t & 63, oi = t >> 6;
#pragma unroll 1
        for (int p = 0; p < 16; ++p) {
            int o2 = oi * 16 + p;
            out[(size_t)b * O * N + (size_t)o2 * N + n0 + j] = res[j][o2];
        }
    }
}

extern "C" void kernel_launch(void* const* d_in, const int* in_sizes, int n_in,
                              void* d_out, int out_size, void* d_ws, size_t ws_size,
                              hipStream_t stream) {
    const float* x     = (const float*)d_in[0];
    const float* W     = (const float*)d_in[1];
    const float* gamma = (const float*)d_in[2];
    const float* beta  = (const float*)d_in[3];
    const int*   kptr  = (const int*)d_in[4];
    float* out = (float*)d_out;

    char* ws = (char*)d_ws;
    float* d_buf = (float*)ws; ws += (size_t)N * N * 4;          // 64 MB (per-batch, reused)
    float* xx    = (float*)ws; ws += (size_t)B * N * 4;
    int*   idx   = (int*)ws;   ws += (size_t)B * N * KMAX * 4;
    float* u_t   = (float*)ws; ws += (size_t)B * N * O * 4;
    float* v_t   = (float*)ws; ws += (size_t)B * N * O * 4;
    float* ymax  = (float*)ws; ws += (size_t)B * N * O * 4;
    float* ymin  = (float*)ws; ws += (size_t)B * N * O * 4;
    float* stats = (float*)ws; ws += 512;
    float* scsh  = (float*)ws;

    hipMemsetAsync(stats, 0, 512, stream);
    ec_xx<<<B * N / 256, 256, 0, stream>>>(x, xx);
    ec_uv<<<B * N / 64, 256, 0, stream>>>(x, W, u_t, v_t);
    for (int b = 0; b < B; ++b) {
        dim3 g(N / 128, N / 128);
        ec_gemm<<<g, 256, 0, stream>>>(x, xx, d_buf, b);
        ec_topk<<<N / 4, 256, 0, stream>>>(d_buf, kptr, idx, b);
    }
    ec_stats<<<B * N / 64, 256, 0, stream>>>(u_t, v_t, idx, kptr, ymax, ymin, stats);
    ec_final<<<1, 64, 0, stream>>>(stats, gamma, beta, kptr, scsh);
    ec_out<<<B * N / 64, 256, 0, stream>>>(ymax, ymin, scsh, out);
}

// Round 3
// 962.420 us; speedup vs baseline: 1.0699x; 1.0699x over previous
//
#include <hip/hip_runtime.h>
#include <float.h>

#define B 8
#define C 64
#define N 4096
#define O 64
#define KMAX 32

// ---------------- xx[b,n] = sum_c x[b,c,n]^2 ----------------
__global__ __launch_bounds__(256) void ec_xx(const float* __restrict__ x,
                                             float* __restrict__ xx) {
    int i = blockIdx.x * 256 + threadIdx.x;   // b*N + n
    int b = i >> 12;
    int n = i & (N - 1);
    const float* xb = x + (size_t)b * C * N + n;
    float acc = 0.f;
#pragma unroll
    for (int c = 0; c < C; ++c) {
        float t = xb[(size_t)c * N];
        acc += t * t;
    }
    xx[i] = acc;
}

// ---------------- d[n,m] = 2*dot(x_n,x_m) - xx[m]  (one batch) ----------------
__global__ __launch_bounds__(256) void ec_gemm(const float* __restrict__ x,
                                               const float* __restrict__ xx,
                                               float* __restrict__ d, int b) {
    __shared__ float As[C][128];
    __shared__ float Bs[C][128];
    const int m0 = blockIdx.x * 128;
    const int n0 = blockIdx.y * 128;
    const float* xb = x + (size_t)b * C * N;
    const int t = threadIdx.x;

    const float4* xa = (const float4*)xb;
#pragma unroll
    for (int p = 0; p < 8; ++p) {
        int q = t + 256 * p;          // 0..2047
        int c = q >> 5;               // 64 rows
        int j4 = q & 31;              // 32 float4 per row
        float4 va = xa[(size_t)c * (N / 4) + (n0 >> 2) + j4];
        *((float4*)&As[c][j4 * 4]) = va;
        float4 vb = xa[(size_t)c * (N / 4) + (m0 >> 2) + j4];
        *((float4*)&Bs[c][j4 * 4]) = vb;
    }
    __syncthreads();

    const int tx = t & 15;            // m micro
    const int ty = t >> 4;            // n micro
    float acc[8][8] = {};
#pragma unroll 4
    for (int k = 0; k < C; ++k) {
        float a[8], bb[8];
        *(float4*)&a[0]  = *(float4*)&As[k][ty * 8];
        *(float4*)&a[4]  = *(float4*)&As[k][ty * 8 + 4];
        *(float4*)&bb[0] = *(float4*)&Bs[k][tx * 8];
        *(float4*)&bb[4] = *(float4*)&Bs[k][tx * 8 + 4];
#pragma unroll
        for (int i = 0; i < 8; ++i)
#pragma unroll
            for (int j = 0; j < 8; ++j)
                acc[i][j] += a[i] * bb[j];
    }

    float xm[8];
    *(float4*)&xm[0] = *(const float4*)&xx[(size_t)b * N + m0 + tx * 8];
    *(float4*)&xm[4] = *(const float4*)&xx[(size_t)b * N + m0 + tx * 8 + 4];
#pragma unroll
    for (int i = 0; i < 8; ++i) {
        int n = n0 + ty * 8 + i;
        float4 o0, o1;
        o0.x = 2.f * acc[i][0] - xm[0];
        o0.y = 2.f * acc[i][1] - xm[1];
        o0.z = 2.f * acc[i][2] - xm[2];
        o0.w = 2.f * acc[i][3] - xm[3];
        o1.x = 2.f * acc[i][4] - xm[4];
        o1.y = 2.f * acc[i][5] - xm[5];
        o1.z = 2.f * acc[i][6] - xm[6];
        o1.w = 2.f * acc[i][7] - xm[7];
        *(float4*)&d[(size_t)n * N + m0 + tx * 8]     = o0;
        *(float4*)&d[(size_t)n * N + m0 + tx * 8 + 4] = o1;
    }
}

// ---------------- top-k: 1 wave per row, incremental rescan ----------------
// Lane owns columns {4*(lane + 64p) + j : p<16, j<4}. Initial local argmax is
// fused into the staging load; per round only the winner lane rescans.
__global__ __launch_bounds__(256) void ec_topk(const float* __restrict__ d,
                                               const int* __restrict__ kptr,
                                               int* __restrict__ idx, int b) {
    __shared__ float sd[4][N];        // 64 KB
    const int t = threadIdx.x;
    const int w = t >> 6;
    const int lane = t & 63;
    const int n = blockIdx.x * 4 + w;
    const int k = *kptr;
    const float* row = d + (size_t)n * N;
    float* lr = sd[w];

    float v = -FLT_MAX;
    int mi = 0;
#pragma unroll
    for (int p = 0; p < 16; ++p) {
        int f4 = lane + (p << 6);
        float4 q = ((const float4*)row)[f4];
        ((float4*)lr)[f4] = q;
        int m = f4 << 2;
        if (q.x > v) { v = q.x; mi = m; }
        if (q.y > v) { v = q.y; mi = m + 1; }
        if (q.z > v) { v = q.z; mi = m + 2; }
        if (q.w > v) { v = q.w; mi = m + 3; }
    }

    int* out = idx + ((size_t)b * N + n) * KMAX;
    for (int r = 0; r < k; ++r) {
        float bv = v;
        int bmi = mi;
#pragma unroll
        for (int off = 1; off < 64; off <<= 1) {
            float ov = __shfl_xor(bv, off);
            int oi = __shfl_xor(bmi, off);
            if (ov > bv || (ov == bv && oi < bmi)) { bv = ov; bmi = oi; }
        }
        if (lane == 0) out[r] = bmi;
        if (((bmi >> 2) & 63) == lane) {
            lr[bmi] = -FLT_MAX;
            v = -FLT_MAX;
            mi = 0;
#pragma unroll
            for (int p = 0; p < 16; ++p) {
                int f4 = lane + (p << 6);
                float4 q = ((const float4*)lr)[f4];
                int m = f4 << 2;
                if (q.x > v) { v = q.x; mi = m; }
                if (q.y > v) { v = q.y; mi = m + 1; }
                if (q.z > v) { v = q.z; mi = m + 2; }
                if (q.w > v) { v = q.w; mi = m + 3; }
            }
        }
    }
}

// ---------------- u[b,m,o], v[b,n,o] ----------------
__global__ __launch_bounds__(256) void ec_uv(const float* __restrict__ x,
                                             const float* __restrict__ W,
                                             float* __restrict__ u,
                                             float* __restrict__ v) {
    __shared__ float xs[C][64];
    __shared__ float W1[C][64];
    __shared__ float Wd[C][64];
    const int blk = blockIdx.x;        // B * N/64
    const int b = blk >> 6;
    const int m0 = (blk & 63) << 6;
    const int t = threadIdx.x;

#pragma unroll
    for (int p = 0; p < 16; ++p) {
        int q = t + 256 * p;           // 4096
        int c = q >> 6, j = q & 63;
        xs[c][j] = x[(size_t)b * C * N + (size_t)c * N + m0 + j];
    }
#pragma unroll
    for (int p = 0; p < 16; ++p) {
        int q = t + 256 * p;           // (c,o) pairs, 4096
        int c = q >> 6, o = q & 63;
        float w1 = W[o * 128 + c];
        float w2 = W[o * 128 + 64 + c];
        W1[c][o] = w1;
        Wd[c][o] = w2 - w1;
    }
    __syncthreads();

    const int o = t & 63, ji = t >> 6;
#pragma unroll 1
    for (int p = 0; p < 16; ++p) {
        int j = ji + 4 * p;
        float su = 0.f, sv = 0.f;
#pragma unroll
        for (int c = 0; c < C; ++c) {
            float xv = xs[c][j];
            su += xv * W1[c][o];
            sv += xv * Wd[c][o];
        }
        size_t base = ((size_t)b * N + m0 + j) * O + o;
        u[base] = su;
        v[base] = sv;
    }
}

// ---------------- BN stats + per-(b,n,o) gather max/min ----------------
// B*N/16 = 2048 blocks, 16 n each (4 per wave). Neighbor indices prefetched
// into registers (static unroll) -> 20 independent L2 gathers in flight.
__global__ __launch_bounds__(256) void ec_stats(const float* __restrict__ u,
                                                const float* __restrict__ v,
                                                const int* __restrict__ idx,
                                                const int* __restrict__ kptr,
                                                float* __restrict__ ymax,
                                                float* __restrict__ ymin,
                                                float* __restrict__ stats) {
    const int blk = blockIdx.x;        // B * N/16 = 2048
    const int b = blk >> 8;
    const int n0 = (blk & 255) << 4;
    const int t = threadIdx.x;
    const int o = t & 63, w = t >> 6;
    const int k = *kptr;
    const float* ub = u + (size_t)b * N * O;
    float s = 0.f, s2 = 0.f;

#pragma unroll 1
    for (int p = 0; p < 4; ++p) {
        int n = n0 + w * 4 + p;
        size_t rowb = (size_t)b * N + n;
        const int4* ip = (const int4*)(idx + rowb * KMAX);
        int4 q0 = ip[0], q1 = ip[1], q2 = ip[2], q3 = ip[3];
        int4 q4 = ip[4], q5 = ip[5], q6 = ip[6], q7 = ip[7];
        float vv = v[rowb * O + o];
        float gmax = -FLT_MAX, gmin = FLT_MAX, gs = 0.f, gs2 = 0.f;
#define EC_G(mm, pos)                                                        \
        if ((pos) < k) {                                                     \
            float g = ub[(size_t)(unsigned)(mm) * O + o];                    \
            gs += g; gs2 += g * g;                                           \
            gmax = fmaxf(gmax, g); gmin = fminf(gmin, g);                    \
        }
        EC_G(q0.x, 0)  EC_G(q0.y, 1)  EC_G(q0.z, 2)  EC_G(q0.w, 3)
        EC_G(q1.x, 4)  EC_G(q1.y, 5)  EC_G(q1.z, 6)  EC_G(q1.w, 7)
        EC_G(q2.x, 8)  EC_G(q2.y, 9)  EC_G(q2.z, 10) EC_G(q2.w, 11)
        EC_G(q3.x, 12) EC_G(q3.y, 13) EC_G(q3.z, 14) EC_G(q3.w, 15)
        EC_G(q4.x, 16) EC_G(q4.y, 17) EC_G(q4.z, 18) EC_G(q4.w, 19)
        EC_G(q5.x, 20) EC_G(q5.y, 21) EC_G(q5.z, 22) EC_G(q5.w, 23)
        EC_G(q6.x, 24) EC_G(q6.y, 25) EC_G(q6.z, 26) EC_G(q6.w, 27)
        EC_G(q7.x, 28) EC_G(q7.y, 29) EC_G(q7.z, 30) EC_G(q7.w, 31)
#undef EC_G
        float fk = (float)k;
        s  += gs + fk * vv;
        s2 += gs2 + 2.f * vv * gs + fk * vv * vv;
        ymax[rowb * O + o] = gmax + vv;
        ymin[rowb * O + o] = gmin + vv;
    }

    __shared__ float rs[256], rs2[256];
    rs[t] = s;
    rs2[t] = s2;
    __syncthreads();
    if (t < 64) {
        float a  = rs[t] + rs[t + 64] + rs[t + 128] + rs[t + 192];
        float a2 = rs2[t] + rs2[t + 64] + rs2[t + 128] + rs2[t + 192];
        atomicAdd(&stats[t], a);
        atomicAdd(&stats[64 + t], a2);
    }
}

// ---------------- finalize BN affine ----------------
__global__ void ec_final(const float* __restrict__ stats,
                         const float* __restrict__ gamma,
                         const float* __restrict__ beta,
                         const int* __restrict__ kptr,
                         float* __restrict__ scsh) {
    int o = threadIdx.x;               // 64
    int k = *kptr;
    float M = (float)B * (float)N * (float)k;
    float mean = stats[o] / M;
    float var = stats[64 + o] / M - mean * mean;
    var = fmaxf(var, 0.f);
    float sc = gamma[o] * rsqrtf(var + 1e-5f);
    float sh = beta[o] - mean * sc;
    scsh[o] = sc;
    scsh[64 + o] = sh;
}

// ---------------- output: BN + leaky + transpose to (B,O,N) ----------------
__global__ __launch_bounds__(256) void ec_out(const float* __restrict__ ymax,
                                              const float* __restrict__ ymin,
                                              const float* __restrict__ scsh,
                                              float* __restrict__ out) {
    __shared__ float res[64][65];
    const int blk = blockIdx.x;        // B * N/64
    const int b = blk >> 6;
    const int n0 = (blk & 63) << 6;
    const int t = threadIdx.x;
    {
        const int o = t & 63, ni = t >> 6;
        float sc = scsh[o], sh = scsh[64 + o];
#pragma unroll 1
        for (int p = 0; p < 16; ++p) {
            int nl = ni * 16 + p;
            size_t a = ((size_t)b * N + n0 + nl) * O + o;
            float y = (sc >= 0.f) ? ymax[a] : ymin[a];
            float z = sc * y + sh;
            res[nl][o] = (z >= 0.f) ? z : 0.2f * z;
        }
    }
    __syncthreads();
    {
        const int j = t & 63, oi = t >> 6;
#pragma unroll 1
        for (int p = 0; p < 16; ++p) {
            int o2 = oi * 16 + p;
            out[(size_t)b * O * N + (size_t)o2 * N + n0 + j] = res[j][o2];
        }
    }
}

extern "C" void kernel_launch(void* const* d_in, const int* in_sizes, int n_in,
                              void* d_out, int out_size, void* d_ws, size_t ws_size,
                              hipStream_t stream) {
    const float* x     = (const float*)d_in[0];
    const float* W     = (const float*)d_in[1];
    const float* gamma = (const float*)d_in[2];
    const float* beta  = (const float*)d_in[3];
    const int*   kptr  = (const int*)d_in[4];
    float* out = (float*)d_out;

    char* ws = (char*)d_ws;
    float* d_buf = (float*)ws; ws += (size_t)N * N * 4;          // 64 MB (per-batch, reused)
    float* xx    = (float*)ws; ws += (size_t)B * N * 4;
    int*   idx   = (int*)ws;   ws += (size_t)B * N * KMAX * 4;
    float* u_t   = (float*)ws; ws += (size_t)B * N * O * 4;
    float* v_t   = (float*)ws; ws += (size_t)B * N * O * 4;
    float* ymax  = (float*)ws; ws += (size_t)B * N * O * 4;
    float* ymin  = (float*)ws; ws += (size_t)B * N * O * 4;
    float* stats = (float*)ws; ws += 512;
    float* scsh  = (float*)ws;

    hipMemsetAsync(stats, 0, 512, stream);
    ec_xx<<<B * N / 256, 256, 0, stream>>>(x, xx);
    ec_uv<<<B * N / 64, 256, 0, stream>>>(x, W, u_t, v_t);
    for (int b = 0; b < B; ++b) {
        dim3 g(N / 128, N / 128);
        ec_gemm<<<g, 256, 0, stream>>>(x, xx, d_buf, b);
        ec_topk<<<N / 4, 256, 0, stream>>>(d_buf, kptr, idx, b);
    }
    ec_stats<<<B * N / 16, 256, 0, stream>>>(u_t, v_t, idx, kptr, ymax, ymin, stats);
    ec_final<<<1, 64, 0, stream>>>(stats, gamma, beta, kptr, scsh);
    ec_out<<<B * N / 64, 256, 0, stream>>>(ymax, ymin, scsh, out);
}

// Round 4
// 868.171 us; speedup vs baseline: 1.1861x; 1.1086x over previous
//
#include <hip/hip_runtime.h>
#include <hip/hip_fp16.h>
#include <float.h>

#define B 8
#define C 64
#define N 4096
#define O 64
#define KMAX 32
#define KC 32   // approx candidate margin (k=20 exact set re-selected from these)

typedef unsigned short u16;
typedef __attribute__((ext_vector_type(8))) u16 u16x8;
typedef __attribute__((ext_vector_type(8))) short bf16x8;
typedef __attribute__((ext_vector_type(4))) float f32x4;

__device__ __forceinline__ u16 f2bf(float f) {
    unsigned u = __builtin_bit_cast(unsigned, f);
    unsigned r = (u + 0x7FFFu + ((u >> 16) & 1)) >> 16;   // RTNE
    return (u16)r;
}
__device__ __forceinline__ float bf2f(u16 h) {
    return __builtin_bit_cast(float, (unsigned)h << 16);
}

// ---------- prep: xt[b][n][c] fp32, xtb bf16, xx[b][n] ----------
__global__ __launch_bounds__(256) void ec_prep(const float* __restrict__ x,
                                               float* __restrict__ xx,
                                               float* __restrict__ xt,
                                               u16* __restrict__ xtb) {
    __shared__ float xs[64][65];
    __shared__ float rs[4][64];
    const int blk = blockIdx.x;            // B*N/64 = 512
    const int b = blk >> 6;
    const int n0 = (blk & 63) << 6;
    const int t = threadIdx.x;
#pragma unroll
    for (int p = 0; p < 16; ++p) {
        int q = t + 256 * p; int c = q >> 6, j = q & 63;
        xs[c][j] = x[(size_t)b * C * N + (size_t)c * N + n0 + j];
    }
    __syncthreads();
    const int j = t >> 2, g = t & 3;       // row j, c-quarter g
    float vals[16]; float ss = 0.f;
#pragma unroll
    for (int i = 0; i < 16; ++i) { float f = xs[g * 16 + i][j]; vals[i] = f; ss += f * f; }
    rs[g][j] = ss;
    size_t rowb = ((size_t)b * N + n0 + j) * 64 + g * 16;
#pragma unroll
    for (int i = 0; i < 4; ++i) {
        float4 v4 = { vals[4 * i], vals[4 * i + 1], vals[4 * i + 2], vals[4 * i + 3] };
        *(float4*)&xt[rowb + 4 * i] = v4;
    }
    u16x8 h0, h1;
#pragma unroll
    for (int i = 0; i < 8; ++i) { h0[i] = f2bf(vals[i]); h1[i] = f2bf(vals[8 + i]); }
    *(u16x8*)&xtb[rowb] = h0;
    *(u16x8*)&xtb[rowb + 8] = h1;
    __syncthreads();
    if (t < 64) xx[(size_t)b * N + t + n0] = rs[0][t] + rs[1][t] + rs[2][t] + rs[3][t];
}

// ---------- MFMA distance: dbf[n][m] = bf16(2*dot(x_n,x_m) - xx[m]) ----------
__global__ __launch_bounds__(256) void ec_gemm(const u16* __restrict__ xtb,
                                               const float* __restrict__ xx,
                                               u16* __restrict__ dbf, int b) {
    __shared__ u16 lds[18432 + 8];         // 36 KB: staging (32K) then epilogue
    const int t = threadIdx.x;
    const int m0 = blockIdx.x * 128, n0 = blockIdx.y * 128;
    const u16* xa = xtb + (size_t)b * N * 64;
#pragma unroll
    for (int p = 0; p < 4; ++p) {
        int q = t + 256 * p;               // 0..1023
        int row = q >> 3, ch = q & 7;
        int by = (row * 128 + ch * 16) ^ ((row & 7) << 4);
        *(u16x8*)((char*)lds + by) = *(const u16x8*)&xa[(size_t)(n0 + row) * 64 + ch * 8];
        *(u16x8*)((char*)lds + 16384 + by) = *(const u16x8*)&xa[(size_t)(m0 + row) * 64 + ch * 8];
    }
    __syncthreads();
    const int w = t >> 6, lane = t & 63;
    const int wr = w >> 1, wc = w & 1;
    const int fr = lane & 15, fg = lane >> 4;
    f32x4 acc[4][4] = {};
#pragma unroll
    for (int ks = 0; ks < 2; ++ks) {
        bf16x8 af[4], bg[4];
#pragma unroll
        for (int fi = 0; fi < 4; ++fi) {
            int rowA = 64 * wr + 16 * fi + fr;
            int byA = (rowA * 128 + ks * 64 + fg * 16) ^ ((rowA & 7) << 4);
            af[fi] = *(const bf16x8*)((const char*)lds + byA);
            int rowB = 64 * wc + 16 * fi + fr;
            int byB = (rowB * 128 + ks * 64 + fg * 16) ^ ((rowB & 7) << 4);
            bg[fi] = *(const bf16x8*)((const char*)lds + 16384 + byB);
        }
#pragma unroll
        for (int fi = 0; fi < 4; ++fi)
#pragma unroll
            for (int fj = 0; fj < 4; ++fj)
                acc[fi][fj] = __builtin_amdgcn_mfma_f32_16x16x32_bf16(af[fi], bg[fj], acc[fi][fj], 0, 0, 0);
    }
    float xm[4];
#pragma unroll
    for (int fj = 0; fj < 4; ++fj) xm[fj] = xx[(size_t)b * N + m0 + 64 * wc + 16 * fj + fr];
    __syncthreads();                        // all frag reads done before LDS reuse
    u16* ep = lds + w * 64 * 72;            // 144-B row stride (bank spread, 16B aligned)
#pragma unroll
    for (int fi = 0; fi < 4; ++fi)
#pragma unroll
        for (int fj = 0; fj < 4; ++fj)
#pragma unroll
            for (int r = 0; r < 4; ++r) {
                float dv = 2.f * acc[fi][fj][r] - xm[fj];
                int row = 16 * fi + fg * 4 + r, col = 16 * fj + fr; // m89 C/D layout
                ep[row * 72 + col] = f2bf(dv);
            }
    __syncthreads();
    const int rr = lane >> 3, cc = lane & 7;
#pragma unroll
    for (int p = 0; p < 8; ++p) {
        int row = p * 8 + rr;
        u16x8 vv = *(const u16x8*)&ep[row * 72 + cc * 8];
        *(u16x8*)&dbf[(size_t)(n0 + 64 * wr + row) * N + m0 + 64 * wc + cc * 8] = vv;
    }
}

// ---------- top-KC approx (per-lane top-2 cache) + exact fp32 rescore ----------
__global__ __launch_bounds__(256) void ec_topk(const u16* __restrict__ dbf,
                                               const float* __restrict__ xt,
                                               const float* __restrict__ xx,
                                               const int* __restrict__ kptr,
                                               int* __restrict__ idx, int b) {
    __shared__ u16 sd[4][N];               // 32 KB
    __shared__ int scand[4][KC];
    const int t = threadIdx.x, w = t >> 6, lane = t & 63;
    const int n = blockIdx.x * 4 + w;
    const int k = *kptr;
    const u16* drow = dbf + (size_t)n * N;
    u16* lr = sd[w];

    float v1 = -FLT_MAX, v2 = -FLT_MAX; int i1 = -1, i2 = -1;
#pragma unroll
    for (int p = 0; p < 8; ++p) {
        int c8 = lane + (p << 6);
        u16x8 q = *(const u16x8*)&drow[c8 * 8];
        *(u16x8*)&lr[c8 * 8] = q;
#pragma unroll
        for (int jj = 0; jj < 8; ++jj) {
            float f = bf2f(q[jj]); int m = c8 * 8 + jj;
            if (f > v2) {
                if (f > v1) { v2 = v1; i2 = i1; v1 = f; i1 = m; }
                else { v2 = f; i2 = m; }
            }
        }
    }
    int my_cand = 0;
    for (int r = 0; r < KC; ++r) {
        float bv = v1; int bmi = i1;
#pragma unroll
        for (int off = 1; off < 64; off <<= 1) {
            float ov = __shfl_xor(bv, off);
            int oi = __shfl_xor(bmi, off);
            if (ov > bv || (ov == bv && (unsigned)oi < (unsigned)bmi)) { bv = ov; bmi = oi; }
        }
        if (lane == r) my_cand = bmi;
        if (((bmi >> 3) & 63) == lane) {
            lr[bmi] = 0xFF80u;             // bf16 -inf
            v1 = v2; i1 = i2; v2 = -FLT_MAX; i2 = -1;
            if (i1 < 0) {                   // cache empty: rescan own 64 entries
#pragma unroll
                for (int p = 0; p < 8; ++p) {
                    int c8 = lane + (p << 6);
                    u16x8 q = *(const u16x8*)&lr[c8 * 8];
#pragma unroll
                    for (int jj = 0; jj < 8; ++jj) {
                        float f = bf2f(q[jj]); int m = c8 * 8 + jj;
                        if (f > v2) {
                            if (f > v1) { v2 = v1; i2 = i1; v1 = f; i1 = m; }
                            else { v2 = f; i2 = m; }
                        }
                    }
                }
            }
        }
    }
    if (lane < KC) scand[w][lane] = my_cand;
    // exact rescore: lane = channel c
    const float* xtb_ = xt + (size_t)b * N * 64;
    float xnc = xtb_[(size_t)n * 64 + lane];
    float xxc = (lane < KC) ? xx[(size_t)b * N + my_cand] : 0.f;
    float myexact = -FLT_MAX;
#pragma unroll 4
    for (int jc = 0; jc < KC; ++jc) {
        int mj = scand[w][jc];
        float g = xtb_[(size_t)mj * 64 + lane];
        float pp = xnc * g;
#pragma unroll
        for (int off = 1; off < 64; off <<= 1) pp += __shfl_xor(pp, off);
        if (lane == jc) myexact = 2.f * pp - xxc;
    }
    // exact top-k SET among KC candidates (tie -> lower m)
    int out_m = my_cand;
    int* outp = idx + ((size_t)b * N + n) * KMAX;
    for (int r = 0; r < k; ++r) {
        float bv = myexact; int bm = out_m, bl = lane;
#pragma unroll
        for (int off = 1; off < 64; off <<= 1) {
            float ov = __shfl_xor(bv, off);
            int om = __shfl_xor(bm, off);
            int ol = __shfl_xor(bl, off);
            if (ov > bv || (ov == bv && (unsigned)om < (unsigned)bm)) { bv = ov; bm = om; bl = ol; }
        }
        if (lane == 0) outp[r] = bm;
        if (lane == bl) myexact = -FLT_MAX;
    }
}

// ---------- u[b,m,o], v[b,n,o] (fp16) ----------
__global__ __launch_bounds__(256) void ec_uv(const float* __restrict__ x,
                                             const float* __restrict__ W,
                                             __half* __restrict__ u,
                                             __half* __restrict__ v) {
    __shared__ float xs[C][64];
    __shared__ float W1[C][64];
    __shared__ float Wd[C][64];
    const int blk = blockIdx.x;            // B*N/64
    const int b = blk >> 6;
    const int m0 = (blk & 63) << 6;
    const int t = threadIdx.x;
#pragma unroll
    for (int p = 0; p < 16; ++p) {
        int q = t + 256 * p; int c = q >> 6, j = q & 63;
        xs[c][j] = x[(size_t)b * C * N + (size_t)c * N + m0 + j];
    }
#pragma unroll
    for (int p = 0; p < 16; ++p) {
        int q = t + 256 * p; int c = q >> 6, o = q & 63;
        float w1 = W[o * 128 + c];
        float w2 = W[o * 128 + 64 + c];
        W1[c][o] = w1; Wd[c][o] = w2 - w1;
    }
    __syncthreads();
    const int o = t & 63, ji = t >> 6;
#pragma unroll 1
    for (int p = 0; p < 16; ++p) {
        int j = ji + 4 * p;
        float su = 0.f, sv = 0.f;
#pragma unroll
        for (int c = 0; c < C; ++c) {
            float xv = xs[c][j];
            su += xv * W1[c][o];
            sv += xv * Wd[c][o];
        }
        size_t base = ((size_t)b * N + m0 + j) * O + o;
        u[base] = __float2half(su);
        v[base] = __float2half(sv);
    }
}

// ---------- BN stats + packed (max,min) ext ----------
__global__ __launch_bounds__(256) void ec_stats(const __half* __restrict__ u,
                                                const __half* __restrict__ v,
                                                const int* __restrict__ idx,
                                                const int* __restrict__ kptr,
                                                __half2* __restrict__ ext,
                                                float* __restrict__ stats) {
    const int blk = blockIdx.x;            // B*N/16 = 2048
    const int b = blk >> 8;
    const int n0 = (blk & 255) << 4;
    const int t = threadIdx.x;
    const int o = t & 63, w = t >> 6;
    const int k = *kptr;
    const __half* ub = u + (size_t)b * N * O;
    float s = 0.f, s2 = 0.f;
#pragma unroll 2
    for (int p = 0; p < 4; ++p) {
        int n = n0 + w * 4 + p;
        size_t rowb = (size_t)b * N + n;
        const int4* ip = (const int4*)(idx + rowb * KMAX);
        int4 q0 = ip[0], q1 = ip[1], q2 = ip[2], q3 = ip[3];
        int4 q4 = ip[4], q5 = ip[5], q6 = ip[6], q7 = ip[7];
        float vv = __half2float(v[rowb * O + o]);
        float gmax = -FLT_MAX, gmin = FLT_MAX, gs = 0.f, gs2 = 0.f;
#define EC_G(mm, pos)                                                        \
        if ((pos) < k) {                                                     \
            float g = __half2float(ub[(size_t)(unsigned)(mm) * O + o]);      \
            gs += g; gs2 += g * g;                                           \
            gmax = fmaxf(gmax, g); gmin = fminf(gmin, g);                    \
        }
        EC_G(q0.x, 0)  EC_G(q0.y, 1)  EC_G(q0.z, 2)  EC_G(q0.w, 3)
        EC_G(q1.x, 4)  EC_G(q1.y, 5)  EC_G(q1.z, 6)  EC_G(q1.w, 7)
        EC_G(q2.x, 8)  EC_G(q2.y, 9)  EC_G(q2.z, 10) EC_G(q2.w, 11)
        EC_G(q3.x, 12) EC_G(q3.y, 13) EC_G(q3.z, 14) EC_G(q3.w, 15)
        EC_G(q4.x, 16) EC_G(q4.y, 17) EC_G(q4.z, 18) EC_G(q4.w, 19)
        EC_G(q5.x, 20) EC_G(q5.y, 21) EC_G(q5.z, 22) EC_G(q5.w, 23)
        EC_G(q6.x, 24) EC_G(q6.y, 25) EC_G(q6.z, 26) EC_G(q6.w, 27)
        EC_G(q7.x, 28) EC_G(q7.y, 29) EC_G(q7.z, 30) EC_G(q7.w, 31)
#undef EC_G
        float fk = (float)k;
        s  += gs + fk * vv;
        s2 += gs2 + 2.f * vv * gs + fk * vv * vv;
        ext[rowb * O + o] = __halves2half2(__float2half(gmax + vv), __float2half(gmin + vv));
    }
    __shared__ float rs[256], rs2[256];
    rs[t] = s; rs2[t] = s2;
    __syncthreads();
    if (t < 64) {
        float a  = rs[t] + rs[t + 64] + rs[t + 128] + rs[t + 192];
        float a2 = rs2[t] + rs2[t + 64] + rs2[t + 128] + rs2[t + 192];
        atomicAdd(&stats[t], a);
        atomicAdd(&stats[64 + t], a2);
    }
}

// ---------- finalize BN affine ----------
__global__ void ec_final(const float* __restrict__ stats,
                         const float* __restrict__ gamma,
                         const float* __restrict__ beta,
                         const int* __restrict__ kptr,
                         float* __restrict__ scsh) {
    int o = threadIdx.x;                   // 64
    int k = *kptr;
    float M = (float)B * (float)N * (float)k;
    float mean = stats[o] / M;
    float var = stats[64 + o] / M - mean * mean;
    var = fmaxf(var, 0.f);
    float sc = gamma[o] * rsqrtf(var + 1e-5f);
    float sh = beta[o] - mean * sc;
    scsh[o] = sc;
    scsh[64 + o] = sh;
}

// ---------- output: pick extreme by sc sign, BN + leaky, transpose ----------
__global__ __launch_bounds__(256) void ec_out(const __half2* __restrict__ ext,
                                              const float* __restrict__ scsh,
                                              float* __restrict__ out) {
    __shared__ float res[64][65];
    const int blk = blockIdx.x;            // B*N/64
    const int b = blk >> 6;
    const int n0 = (blk & 63) << 6;
    const int t = threadIdx.x;
    {
        const int o = t & 63, ni = t >> 6;
        float sc = scsh[o], sh = scsh[64 + o];
#pragma unroll 1
        for (int p = 0; p < 16; ++p) {
            int nl = ni * 16 + p;
            size_t a = ((size_t)b * N + n0 + nl) * O + o;
            __half2 e = ext[a];
            float y = (sc >= 0.f) ? __low2float(e) : __high2float(e);
            float z = sc * y + sh;
            res[nl][o] = (z >= 0.f) ? z : 0.2f * z;
        }
    }
    __syncthreads();
    {
        const int j = t & 63, oi = t >> 6;
#pragma unroll 1
        for (int p = 0; p < 16; ++p) {
            int o2 = oi * 16 + p;
            out[(size_t)b * O * N + (size_t)o2 * N + n0 + j] = res[j][o2];
        }
    }
}

extern "C" void kernel_launch(void* const* d_in, const int* in_sizes, int n_in,
                              void* d_out, int out_size, void* d_ws, size_t ws_size,
                              hipStream_t stream) {
    const float* x     = (const float*)d_in[0];
    const float* W     = (const float*)d_in[1];
    const float* gamma = (const float*)d_in[2];
    const float* beta  = (const float*)d_in[3];
    const int*   kptr  = (const int*)d_in[4];
    float* out = (float*)d_out;

    char* ws = (char*)d_ws;
    u16*    dbf  = (u16*)ws;    ws += (size_t)N * N * 2;           // 32 MB, per-batch reuse
    float*  xx   = (float*)ws;  ws += (size_t)B * N * 4;
    float*  xt   = (float*)ws;  ws += (size_t)B * N * C * 4;       // 8 MB
    u16*    xtb  = (u16*)ws;    ws += (size_t)B * N * C * 2;       // 4 MB
    int*    idx  = (int*)ws;    ws += (size_t)B * N * KMAX * 4;    // 4 MB
    __half* u_t  = (__half*)ws; ws += (size_t)B * N * O * 2;       // 4 MB
    __half* v_t  = (__half*)ws; ws += (size_t)B * N * O * 2;       // 4 MB
    __half2* ext = (__half2*)ws; ws += (size_t)B * N * O * 4;      // 8 MB
    float* stats = (float*)ws;  ws += 512;
    float* scsh  = (float*)ws;

    hipMemsetAsync(stats, 0, 512, stream);
    ec_prep<<<B * N / 64, 256, 0, stream>>>(x, xx, xt, xtb);
    ec_uv<<<B * N / 64, 256, 0, stream>>>(x, W, u_t, v_t);
    for (int b = 0; b < B; ++b) {
        dim3 g(N / 128, N / 128);
        ec_gemm<<<g, 256, 0, stream>>>(xtb, xx, dbf, b);
        ec_topk<<<N / 4, 256, 0, stream>>>(dbf, xt, xx, kptr, idx, b);
    }
    ec_stats<<<B * N / 16, 256, 0, stream>>>(u_t, v_t, idx, kptr, ext, stats);
    ec_final<<<1, 64, 0, stream>>>(stats, gamma, beta, kptr, scsh);
    ec_out<<<B * N / 64, 256, 0, stream>>>(ext, scsh, out);
}

// Round 5
// 513.344 us; speedup vs baseline: 2.0059x; 1.6912x over previous
//
#include <hip/hip_runtime.h>
#include <hip/hip_fp16.h>
#include <float.h>

#define B 8
#define C 64
#define N 4096
#define O 64
#define KMAX 32
#define KC 32   // approx candidate count (exact top-k set re-selected from these)

typedef unsigned short u16;
typedef __attribute__((ext_vector_type(8))) u16 u16x8;
typedef __attribute__((ext_vector_type(8))) short bf16x8;
typedef __attribute__((ext_vector_type(4))) float f32x4;

__device__ __forceinline__ u16 f2bf(float f) {
    unsigned u = __builtin_bit_cast(unsigned, f);
    unsigned r = (u + 0x7FFFu + ((u >> 16) & 1)) >> 16;   // RTNE
    return (u16)r;
}

// ---------- fused prep: xt fp32, xtb bf16, xx, u/v fp16 ----------
__global__ __launch_bounds__(256) void ec_prep(const float* __restrict__ x,
                                               const float* __restrict__ W,
                                               float* __restrict__ xx,
                                               float* __restrict__ xt,
                                               u16* __restrict__ xtb,
                                               __half* __restrict__ u,
                                               __half* __restrict__ v) {
    __shared__ float xs[64][65];
    __shared__ float W1[C][64];
    __shared__ float Wd[C][64];
    __shared__ float rs[4][64];
    const int blk = blockIdx.x;            // B*N/64 = 512
    const int b = blk >> 6;
    const int n0 = (blk & 63) << 6;
    const int t = threadIdx.x;
#pragma unroll
    for (int p = 0; p < 16; ++p) {
        int q = t + 256 * p; int c = q >> 6, j = q & 63;
        xs[c][j] = x[(size_t)b * C * N + (size_t)c * N + n0 + j];
    }
#pragma unroll
    for (int p = 0; p < 16; ++p) {
        int q = t + 256 * p; int c = q >> 6, o = q & 63;
        float w1 = W[o * 128 + c];
        float w2 = W[o * 128 + 64 + c];
        W1[c][o] = w1; Wd[c][o] = w2 - w1;
    }
    __syncthreads();
    // phase A: transpose out + norms
    {
        const int j = t >> 2, g = t & 3;
        float vals[16]; float ss = 0.f;
#pragma unroll
        for (int i = 0; i < 16; ++i) { float f = xs[g * 16 + i][j]; vals[i] = f; ss += f * f; }
        rs[g][j] = ss;
        size_t rowb = ((size_t)b * N + n0 + j) * 64 + g * 16;
#pragma unroll
        for (int i = 0; i < 4; ++i) {
            float4 v4 = { vals[4 * i], vals[4 * i + 1], vals[4 * i + 2], vals[4 * i + 3] };
            *(float4*)&xt[rowb + 4 * i] = v4;
        }
        u16x8 h0, h1;
#pragma unroll
        for (int i = 0; i < 8; ++i) { h0[i] = f2bf(vals[i]); h1[i] = f2bf(vals[8 + i]); }
        *(u16x8*)&xtb[rowb] = h0;
        *(u16x8*)&xtb[rowb + 8] = h1;
    }
    // phase B: u/v projection
    {
        const int o = t & 63, ji = t >> 6;
#pragma unroll 1
        for (int p = 0; p < 16; ++p) {
            int j = ji + 4 * p;
            float su = 0.f, sv = 0.f;
#pragma unroll
            for (int c = 0; c < C; ++c) {
                float xv = xs[c][j];
                su += xv * W1[c][o];
                sv += xv * Wd[c][o];
            }
            size_t base = ((size_t)b * N + n0 + j) * O + o;
            u[base] = __float2half(su);
            v[base] = __float2half(sv);
        }
    }
    __syncthreads();
    if (t < 64) xx[(size_t)b * N + t + n0] = rs[0][t] + rs[1][t] + rs[2][t] + rs[3][t];
}

// ---------- MFMA distance: dbf[zz][n][m] = bf16(2*dot - xx[m]), 2 batches ----------
__global__ __launch_bounds__(256) void ec_gemm(const u16* __restrict__ xtb,
                                               const float* __restrict__ xx,
                                               u16* __restrict__ dbf, int b0) {
    __shared__ u16 lds[18432 + 8];
    const int t = threadIdx.x;
    const int m0 = blockIdx.x * 128, n0 = blockIdx.y * 128;
    const int zz = blockIdx.z, b = b0 + zz;
    const u16* xa = xtb + (size_t)b * N * 64;
#pragma unroll
    for (int p = 0; p < 4; ++p) {
        int q = t + 256 * p;
        int row = q >> 3, ch = q & 7;
        int by = (row * 128 + ch * 16) ^ ((row & 7) << 4);
        *(u16x8*)((char*)lds + by) = *(const u16x8*)&xa[(size_t)(n0 + row) * 64 + ch * 8];
        *(u16x8*)((char*)lds + 16384 + by) = *(const u16x8*)&xa[(size_t)(m0 + row) * 64 + ch * 8];
    }
    __syncthreads();
    const int w = t >> 6, lane = t & 63;
    const int wr = w >> 1, wc = w & 1;
    const int fr = lane & 15, fg = lane >> 4;
    f32x4 acc[4][4] = {};
#pragma unroll
    for (int ks = 0; ks < 2; ++ks) {
        bf16x8 af[4], bg[4];
#pragma unroll
        for (int fi = 0; fi < 4; ++fi) {
            int rowA = 64 * wr + 16 * fi + fr;
            int byA = (rowA * 128 + ks * 64 + fg * 16) ^ ((rowA & 7) << 4);
            af[fi] = *(const bf16x8*)((const char*)lds + byA);
            int rowB = 64 * wc + 16 * fi + fr;
            int byB = (rowB * 128 + ks * 64 + fg * 16) ^ ((rowB & 7) << 4);
            bg[fi] = *(const bf16x8*)((const char*)lds + 16384 + byB);
        }
#pragma unroll
        for (int fi = 0; fi < 4; ++fi)
#pragma unroll
            for (int fj = 0; fj < 4; ++fj)
                acc[fi][fj] = __builtin_amdgcn_mfma_f32_16x16x32_bf16(af[fi], bg[fj], acc[fi][fj], 0, 0, 0);
    }
    float xm[4];
#pragma unroll
    for (int fj = 0; fj < 4; ++fj) xm[fj] = xx[(size_t)b * N + m0 + 64 * wc + 16 * fj + fr];
    __syncthreads();
    u16* ep = lds + w * 64 * 72;
#pragma unroll
    for (int fi = 0; fi < 4; ++fi)
#pragma unroll
        for (int fj = 0; fj < 4; ++fj)
#pragma unroll
            for (int r = 0; r < 4; ++r) {
                float dv = 2.f * acc[fi][fj][r] - xm[fj];
                int row = 16 * fi + fg * 4 + r, col = 16 * fj + fr;
                ep[row * 72 + col] = f2bf(dv);
            }
    __syncthreads();
    const int rr = lane >> 3, cc = lane & 7;
#pragma unroll
    for (int p = 0; p < 8; ++p) {
        int row = p * 8 + rr;
        u16x8 vv = *(const u16x8*)&ep[row * 72 + cc * 8];
        *(u16x8*)&dbf[(size_t)zz * N * N + (size_t)(n0 + 64 * wr + row) * N + m0 + 64 * wc + cc * 8] = vv;
    }
}

// ---------- top-KC (packed sortable keys) + lane-parallel exact rescore ----------
__global__ __launch_bounds__(256) void ec_topk(const u16* __restrict__ dbf,
                                               const float* __restrict__ xt,
                                               const float* __restrict__ xx,
                                               const int* __restrict__ kptr,
                                               int* __restrict__ idx, int b0) {
    __shared__ u16 sd[4][N];               // sortable u16, 32 KB
    __shared__ int scand[4][KC];
    __shared__ float sxn[4][64];
    const int t = threadIdx.x, w = t >> 6, lane = t & 63;
    const int zz = blockIdx.y, b = b0 + zz;
    const int n = blockIdx.x * 4 + w;
    const int k = *kptr;
    const u16* drow = dbf + (size_t)zz * N * N + (size_t)n * N;
    u16* lr = sd[w];

    // stage (as sortable) + per-lane top-2 packed keys
    unsigned k1 = 0, k2 = 0;
#pragma unroll
    for (int p = 0; p < 8; ++p) {
        int c8 = lane + (p << 6);
        u16x8 q = *(const u16x8*)&drow[c8 * 8];
        u16x8 s;
#pragma unroll
        for (int jj = 0; jj < 8; ++jj)
            s[jj] = q[jj] ^ (u16)((q[jj] & 0x8000u) ? 0xFFFFu : 0x8000u);
        *(u16x8*)&lr[c8 * 8] = s;
#pragma unroll
        for (int jj = 0; jj < 8; ++jj) {
            unsigned key = ((unsigned)s[jj] << 12) | (unsigned)(c8 * 8 + jj);
            if (key > k2) { if (key > k1) { k2 = k1; k1 = key; } else k2 = key; }
        }
    }
    int my_cand = 0;
#pragma unroll 1
    for (int r = 0; r < KC; ++r) {
        unsigned bk = k1;
#pragma unroll
        for (int off = 1; off < 64; off <<= 1) {
            unsigned ov = __shfl_xor(bk, off);
            bk = bk > ov ? bk : ov;
        }
        int m = (int)(bk & 0xFFFu);
        if (lane == r) my_cand = m;
        if (((m >> 3) & 63) == lane) {
            lr[m] = 0;
            k1 = k2; k2 = 0;
            if (k1 == 0) {                  // cache empty: rescan own 512 entries
#pragma unroll
                for (int p = 0; p < 8; ++p) {
                    int c8 = lane + (p << 6);
                    u16x8 s = *(const u16x8*)&lr[c8 * 8];
#pragma unroll
                    for (int jj = 0; jj < 8; ++jj) {
                        unsigned key = ((unsigned)s[jj] << 12) | (unsigned)(c8 * 8 + jj);
                        if (key > k2) { if (key > k1) { k2 = k1; k1 = key; } else k2 = key; }
                    }
                }
            }
        }
    }
    if (lane < KC) scand[w][lane] = my_cand;
    sxn[w][lane] = xt[((size_t)b * N + n) * 64 + lane];
    // lane-parallel exact rescore: lane = (candidate j, c-half h)
    const float* xt_ = xt + (size_t)b * N * 64;
    const int j = lane & 31, h = lane >> 5;
    const int mj = scand[w][j];
    const float* xr = xt_ + (size_t)mj * 64 + h * 32;
    float acc = 0.f;
#pragma unroll
    for (int q8 = 0; q8 < 8; ++q8) {
        float4 g4 = *(const float4*)&xr[q8 * 4];
        float4 xn4 = *(const float4*)&sxn[w][h * 32 + q8 * 4];
        acc += g4.x * xn4.x + g4.y * xn4.y + g4.z * xn4.z + g4.w * xn4.w;
    }
    acc += __shfl_xor(acc, 32);
    float ex = 2.f * acc - xx[(size_t)b * N + mj];
    unsigned fu = __builtin_bit_cast(unsigned, ex);
    unsigned sf = fu ^ ((fu >> 31) ? 0xFFFFFFFFu : 0x80000000u);
    // exact top-k SET among KC candidates
    int* outp = idx + ((size_t)b * N + n) * KMAX;
#pragma unroll 1
    for (int r = 0; r < k; ++r) {
        unsigned bs = sf;
#pragma unroll
        for (int off = 1; off < 64; off <<= 1) {
            unsigned ov = __shfl_xor(bs, off);
            bs = bs > ov ? bs : ov;
        }
        unsigned long long bal = __ballot(sf == bs);
        int L = __ffsll(bal) - 1;
        int m_win = __shfl(mj, L);
        if (lane == 0) outp[r] = m_win;
        if (mj == m_win) sf = 0;
    }
}

// ---------- BN stats + packed (max,min) ext ----------
__global__ __launch_bounds__(256, 2) void ec_stats(const __half* __restrict__ u,
                                                   const __half* __restrict__ v,
                                                   const int* __restrict__ idx,
                                                   const int* __restrict__ kptr,
                                                   __half2* __restrict__ ext,
                                                   float* __restrict__ stats) {
    const int blk = blockIdx.x;            // B*N/16 = 2048
    const int b = blk >> 8;
    const int n0 = (blk & 255) << 4;
    const int t = threadIdx.x;
    const int o = t & 63, w = t >> 6;
    const int k = *kptr;
    const __half* ub = u + (size_t)b * N * O;
    float s = 0.f, s2 = 0.f;
    if (k == 20) {
#pragma unroll
        for (int p = 0; p < 4; ++p) {
            int n = n0 + w * 4 + p;
            size_t rowb = (size_t)b * N + n;
            const int4* ip = (const int4*)(idx + rowb * KMAX);
            int4 q0 = ip[0], q1 = ip[1], q2 = ip[2], q3 = ip[3], q4 = ip[4];
            float vv = __half2float(v[rowb * O + o]);
            float gmax = -FLT_MAX, gmin = FLT_MAX, gs = 0.f, gs2 = 0.f;
#define EC_G(mm)                                                             \
            {                                                                \
                float g = __half2float(ub[(size_t)(unsigned)(mm) * O + o]);  \
                gs += g; gs2 += g * g;                                       \
                gmax = fmaxf(gmax, g); gmin = fminf(gmin, g);                \
            }
            EC_G(q0.x) EC_G(q0.y) EC_G(q0.z) EC_G(q0.w)
            EC_G(q1.x) EC_G(q1.y) EC_G(q1.z) EC_G(q1.w)
            EC_G(q2.x) EC_G(q2.y) EC_G(q2.z) EC_G(q2.w)
            EC_G(q3.x) EC_G(q3.y) EC_G(q3.z) EC_G(q3.w)
            EC_G(q4.x) EC_G(q4.y) EC_G(q4.z) EC_G(q4.w)
#undef EC_G
            s  += gs + 20.f * vv;
            s2 += gs2 + 2.f * vv * gs + 20.f * vv * vv;
            ext[rowb * O + o] = __halves2half2(__float2half(gmax + vv), __float2half(gmin + vv));
        }
    } else {
#pragma unroll 1
        for (int p = 0; p < 4; ++p) {
            int n = n0 + w * 4 + p;
            size_t rowb = (size_t)b * N + n;
            const int* ip = idx + rowb * KMAX;
            float vv = __half2float(v[rowb * O + o]);
            float gmax = -FLT_MAX, gmin = FLT_MAX, gs = 0.f, gs2 = 0.f;
            for (int kk = 0; kk < k; ++kk) {
                int m = ip[kk];
                float g = __half2float(ub[(size_t)(unsigned)m * O + o]);
                gs += g; gs2 += g * g;
                gmax = fmaxf(gmax, g); gmin = fminf(gmin, g);
            }
            float fk = (float)k;
            s  += gs + fk * vv;
            s2 += gs2 + 2.f * vv * gs + fk * vv * vv;
            ext[rowb * O + o] = __halves2half2(__float2half(gmax + vv), __float2half(gmin + vv));
        }
    }
    __shared__ float rsum[256], rsum2[256];
    rsum[t] = s; rsum2[t] = s2;
    __syncthreads();
    if (t < 64) {
        float a  = rsum[t] + rsum[t + 64] + rsum[t + 128] + rsum[t + 192];
        float a2 = rsum2[t] + rsum2[t + 64] + rsum2[t + 128] + rsum2[t + 192];
        atomicAdd(&stats[t], a);
        atomicAdd(&stats[64 + t], a2);
    }
}

// ---------- finalize BN affine ----------
__global__ void ec_final(const float* __restrict__ stats,
                         const float* __restrict__ gamma,
                         const float* __restrict__ beta,
                         const int* __restrict__ kptr,
                         float* __restrict__ scsh) {
    int o = threadIdx.x;                   // 64
    int k = *kptr;
    float M = (float)B * (float)N * (float)k;
    float mean = stats[o] / M;
    float var = stats[64 + o] / M - mean * mean;
    var = fmaxf(var, 0.f);
    float sc = gamma[o] * rsqrtf(var + 1e-5f);
    float sh = beta[o] - mean * sc;
    scsh[o] = sc;
    scsh[64 + o] = sh;
}

// ---------- output: pick extreme by sc sign, BN + leaky, transpose ----------
__global__ __launch_bounds__(256) void ec_out(const __half2* __restrict__ ext,
                                              const float* __restrict__ scsh,
                                              float* __restrict__ out) {
    __shared__ float res[64][65];
    const int blk = blockIdx.x;            // B*N/64
    const int b = blk >> 6;
    const int n0 = (blk & 63) << 6;
    const int t = threadIdx.x;
    {
        const int o = t & 63, ni = t >> 6;
        float sc = scsh[o], sh = scsh[64 + o];
#pragma unroll 1
        for (int p = 0; p < 16; ++p) {
            int nl = ni * 16 + p;
            size_t a = ((size_t)b * N + n0 + nl) * O + o;
            __half2 e = ext[a];
            float y = (sc >= 0.f) ? __low2float(e) : __high2float(e);
            float z = sc * y + sh;
            res[nl][o] = (z >= 0.f) ? z : 0.2f * z;
        }
    }
    __syncthreads();
    {
        const int j = t & 63, oi = t >> 6;
#pragma unroll 1
        for (int p = 0; p < 16; ++p) {
            int o2 = oi * 16 + p;
            out[(size_t)b * O * N + (size_t)o2 * N + n0 + j] = res[j][o2];
        }
    }
}

extern "C" void kernel_launch(void* const* d_in, const int* in_sizes, int n_in,
                              void* d_out, int out_size, void* d_ws, size_t ws_size,
                              hipStream_t stream) {
    const float* x     = (const float*)d_in[0];
    const float* W     = (const float*)d_in[1];
    const float* gamma = (const float*)d_in[2];
    const float* beta  = (const float*)d_in[3];
    const int*   kptr  = (const int*)d_in[4];
    float* out = (float*)d_out;

    char* ws = (char*)d_ws;
    u16*    dbf  = (u16*)ws;    ws += (size_t)2 * N * N * 2;       // 64 MB, 2 batches
    float*  xx   = (float*)ws;  ws += (size_t)B * N * 4;
    float*  xt   = (float*)ws;  ws += (size_t)B * N * C * 4;       // 8 MB
    u16*    xtb  = (u16*)ws;    ws += (size_t)B * N * C * 2;       // 4 MB
    int*    idx  = (int*)ws;    ws += (size_t)B * N * KMAX * 4;    // 4 MB
    __half* u_t  = (__half*)ws; ws += (size_t)B * N * O * 2;       // 4 MB
    __half* v_t  = (__half*)ws; ws += (size_t)B * N * O * 2;       // 4 MB
    __half2* ext = (__half2*)ws; ws += (size_t)B * N * O * 4;      // 8 MB
    float* stats = (float*)ws;  ws += 512;
    float* scsh  = (float*)ws;

    hipMemsetAsync(stats, 0, 512, stream);
    ec_prep<<<B * N / 64, 256, 0, stream>>>(x, W, xx, xt, xtb, u_t, v_t);
    for (int pb = 0; pb < 4; ++pb) {
        ec_gemm<<<dim3(N / 128, N / 128, 2), 256, 0, stream>>>(xtb, xx, dbf, 2 * pb);
        ec_topk<<<dim3(N / 4, 2), 256, 0, stream>>>(dbf, xt, xx, kptr, idx, 2 * pb);
    }
    ec_stats<<<B * N / 16, 256, 0, stream>>>(u_t, v_t, idx, kptr, ext, stats);
    ec_final<<<1, 64, 0, stream>>>(stats, gamma, beta, kptr, scsh);
    ec_out<<<B * N / 64, 256, 0, stream>>>(ext, scsh, out);
}